// Round 3
// baseline (519.609 us; speedup 1.0000x reference)
//
#include <hip/hip_runtime.h>
#include <math.h>

// Problem constants
#define FD   256
#define NH   4
#define SP3  8
#define NP   32          // SP3*NH aux points per query
#define EDIM 64          // FD/NH
#define H    128
#define NS   1024
#define BS   4
#define QTF  4           // queries per featk block (512 blocks -> 2/CU)
#define QTE  4           // queries per epik block  (512 blocks -> 2/CU)

#define TEX         (H*H)              // 16384 texels per (plane,b)
#define BATCH_ELEMS (TEX*FD)           // 4,194,304 floats
#define PAIR_B      2                  // batches processed per pass
#define PAIR_Q      (PAIR_B*NS)        // 2048 queries per pass
#define PPLANE      (PAIR_B*BATCH_ELEMS) // per-plane elems in pair buffer

// ---- workspace layout (float offsets). Total ~114.05 MB.
// ws_size proven >= 114 MB (rounds 3/5 passed); 228 MB overflowed (round 2).
#define WS_PLANES 0
#define WS_FEAT   (3*PPLANE)                       // [2048][256]
#define WS_QK     (WS_FEAT + PAIR_Q*FD)            // [2048][256]
#define WS_AUX    (WS_QK   + PAIR_Q*FD)            // [2048][96]
#define WS_WF     (WS_AUX  + PAIR_Q*NP*3)          // [2048][4][256]
#define WS_PERM   (WS_WF   + PAIR_Q*NH*FD)         // [2 pairs][2048] uint

// bf16 helpers (round-to-nearest-even). Used ONLY on the wf path (af after
// the fp32 sim dot) — sim-path quantization is amplified ~176x and is fatal.
__device__ __forceinline__ unsigned short f2bf(float f) {
  unsigned b = __float_as_uint(f);
  return (unsigned short)((b + 0x7FFFu + ((b >> 16) & 1u)) >> 16);
}
__device__ __forceinline__ float bf2f(unsigned short u) {
  return __uint_as_float(((unsigned)u) << 16);
}

// ---------------------------------------------------------------------------
// K1: transpose planes [B,C,H,W] -> [b-pair][H*W,C] (channel-last).
// 32-texel x 256-channel tiles; LDS 33 KB -> 4 blocks/CU.
// ---------------------------------------------------------------------------
__global__ __launch_bounds__(256) void tpk2(
    const float* __restrict__ xz, const float* __restrict__ xy,
    const float* __restrict__ yz, float* __restrict__ dstAll, int b0)
{
  int bid = blockIdx.x;
  int tT = bid & 511; bid >>= 9;     // 512 texel-tiles of 32
  int bl = bid & 1;   bid >>= 1;     // local batch in pair
  int pl = bid;                      // plane
  const float* src = pl == 0 ? xz : (pl == 1 ? xy : yz);
  float* dst = dstAll + (size_t)pl * PPLANE + (size_t)bl * BATCH_ELEMS;
  int b = b0 + bl;

  __shared__ float T[32 * 260];      // T[texel][channel], stride 260
  int lane = threadIdx.x & 63, w = threadIdx.x >> 6;
  int tex4 = (lane & 7) * 4;         // 0,4,..,28
  int csub = lane >> 3;              // 0..7

  const float* sbase = src + (size_t)b * FD * TEX + tT * 32;
  #pragma unroll
  for (int i = 0; i < 8; i++) {
    int c = i * 32 + w * 8 + csub;   // covers 0..255
    float4 v = *(const float4*)(sbase + (size_t)c * TEX + tex4);
    T[(tex4 + 0) * 260 + c] = v.x;
    T[(tex4 + 1) * 260 + c] = v.y;
    T[(tex4 + 2) * 260 + c] = v.z;
    T[(tex4 + 3) * 260 + c] = v.w;
  }
  __syncthreads();
  #pragma unroll
  for (int i = 0; i < 8; i++) {
    int t = w * 8 + i;
    float4 v = *(const float4*)(&T[t * 260 + lane * 4]);
    *(float4*)(dst + (size_t)(tT * 32 + t) * FD + lane * 4) = v;  // 1KB/wave
  }
}

// ---------------------------------------------------------------------------
// K1b: counting-sort the pair's 2048 queries into 256 buckets =
// (batch<<7)|top-7-Morton-bits. Any permutation is correctness-neutral;
// bucket granularity (~8 queries/cell) is all the locality we measured to
// matter. One block per pair, O(n), ~3 barriers.
// ---------------------------------------------------------------------------
__device__ __forceinline__ unsigned mort7(unsigned v) {   // 7 bits -> every 3rd
  unsigned r = 0;
  #pragma unroll
  for (int i = 0; i < 7; i++) r |= ((v >> i) & 1u) << (3 * i);
  return r;
}

__global__ __launch_bounds__(1024) void sortk(
    const float* __restrict__ qpos, unsigned* __restrict__ perm)
{
  const int pair = blockIdx.x;
  const int b0 = pair * PAIR_B;
  const int t = threadIdx.x;
  __shared__ unsigned cnt[256];
  __shared__ unsigned base[256];
  if (t < 256) cnt[t] = 0;
  __syncthreads();
  unsigned myb[2];
  #pragma unroll
  for (int r = 0; r < 2; r++) {
    int i = t + r * 1024;
    size_t qg = (size_t)b0 * NS + i;
    float x = fminf(fmaxf(qpos[qg * 3 + 0], 0.f), 1.f);
    float y = fminf(fmaxf(qpos[qg * 3 + 1], 0.f), 1.f);
    float z = fminf(fmaxf(qpos[qg * 3 + 2], 0.f), 1.f);
    unsigned m = (mort7((unsigned)(x * 127.f)) << 2)
               | (mort7((unsigned)(y * 127.f)) << 1)
               |  mort7((unsigned)(z * 127.f));          // 21 bits
    unsigned bkt = ((unsigned)(i >> 10) << 7) | (m >> 14);
    myb[r] = bkt;
    atomicAdd(&cnt[bkt], 1u);
  }
  __syncthreads();
  if (t == 0) {
    unsigned s = 0;
    for (int k = 0; k < 256; k++) { base[k] = s; s += cnt[k]; }
  }
  __syncthreads();
  #pragma unroll
  for (int r = 0; r < 2; r++) {
    int i = t + r * 1024;
    unsigned pos = atomicAdd(&base[myb[r]], 1u);
    perm[(size_t)pair * PAIR_Q + pos] = (unsigned)i;
  }
}

// ---------------------------------------------------------------------------
// Bilinear helpers (channel-last plane)
// ---------------------------------------------------------------------------
__device__ __forceinline__ float sample_plane(const float* __restrict__ p,
                                              float u, float v) {
  float x = fminf(fmaxf(u, 0.f), 1.f) * (float)(H - 1);
  float y = fminf(fmaxf(v, 0.f), 1.f) * (float)(H - 1);
  float xf = floorf(x), yf = floorf(y);
  int x0 = (int)xf, y0 = (int)yf;
  float wx = x - xf, wy = y - yf;
  int dx = (x0 < H - 1) ? FD : 0;
  int dy = (y0 < H - 1) ? H * FD : 0;
  int i00 = (y0 * H + x0) * FD;
  float f00 = p[i00], f01 = p[i00 + dx], f10 = p[i00 + dy], f11 = p[i00 + dy + dx];
  float a = f00 + wx * (f01 - f00);
  float b = f10 + wx * (f11 - f10);
  return a + wy * (b - a);
}

__device__ __forceinline__ void setup_samp(int* si, float* sw, float u, float v) {
  float x = fminf(fmaxf(u, 0.f), 1.f) * (float)(H - 1);
  float y = fminf(fmaxf(v, 0.f), 1.f) * (float)(H - 1);
  float xf = floorf(x), yf = floorf(y);
  int x0 = (int)xf, y0 = (int)yf;
  float wx = x - xf, wy = y - yf;
  si[0] = (y0 * H + x0) * FD;
  si[1] = (x0 < H - 1) ? FD : 0;
  si[2] = (y0 < H - 1) ? H * FD : 0;
  sw[0] = (1.f - wy) * (1.f - wx);
  sw[1] = (1.f - wy) * wx;
  sw[2] = wy * (1.f - wx);
  sw[3] = wy * wx;
}

// ---------------------------------------------------------------------------
// K2: per 4-query tile: feature sampling + offsets/aux + q-projection + qk.
// qk[q][c] = sum_e q_scaled[e] * w_k[c][e];  (q . b_k cancels in softmax)
// QTF=4 -> 512 blocks -> 2 blocks/CU (was 1/CU at QT=8: latency-exposed).
// ---------------------------------------------------------------------------
__global__ __launch_bounds__(256) void featk(
    const float* __restrict__ qpos, const float* __restrict__ planesT,
    const float* __restrict__ w_off, const float* __restrict__ b_off,
    const float* __restrict__ w_q, const float* __restrict__ b_q,
    const float* __restrict__ w_k,
    float* __restrict__ feat, float* __restrict__ aux, float* __restrict__ qk,
    int b0)
{
  const int tid = threadIdx.x;
  const int q0l = blockIdx.x * QTF;         // local query base in pair
  const int bl = q0l >> 10;                 // local batch
  __shared__ float s_feat[QTF * 260];
  __shared__ float s_q[QTF * 68];

  const float* Pxz = planesT + 0 * (size_t)PPLANE + (size_t)bl * BATCH_ELEMS + tid;
  const float* Pxy = planesT + 1 * (size_t)PPLANE + (size_t)bl * BATCH_ELEMS + tid;
  const float* Pyz = planesT + 2 * (size_t)PPLANE + (size_t)bl * BATCH_ELEMS + tid;

  for (int qs = 0; qs < QTF; qs++) {
    size_t qg = (size_t)b0 * NS + q0l + qs; // global query for qpos
    float px = qpos[qg * 3 + 0], py = qpos[qg * 3 + 1], pz = qpos[qg * 3 + 2];
    float f = sample_plane(Pxz, px, pz) + sample_plane(Pxy, px, py)
            + sample_plane(Pyz, py, pz);
    s_feat[qs * 260 + tid] = f;
    feat[(size_t)(q0l + qs) * FD + tid] = f;
  }
  __syncthreads();

  // offsets -> aux. thread t<192: half=t/96 handles 2 queries for column j.
  if (tid < 192) {
    int half = tid / 96, j = tid - half * 96;
    float acc[2];
    float bj = b_off[j];
    acc[0] = bj; acc[1] = bj;
    for (int c = 0; c < FD; c++) {
      float wv = w_off[c * 96 + j];
      #pragma unroll
      for (int k = 0; k < 2; k++)
        acc[k] = fmaf(s_feat[(half * 2 + k) * 260 + c], wv, acc[k]);
    }
    int d = j % 3;
    #pragma unroll
    for (int k = 0; k < 2; k++) {
      int qs = half * 2 + k;
      size_t qg = (size_t)b0 * NS + q0l + qs;
      aux[(size_t)(q0l + qs) * 96 + j] = acc[k] + qpos[qg * 3 + d];
    }
  }
  // q projection (scaled by sqrt(E)=8); wave g handles query g
  {
    int e = tid & 63, g = tid >> 6;
    float a = b_q[e];
    for (int c = 0; c < FD; c++)
      a = fmaf(s_feat[g * 260 + c], w_q[c * EDIM + e], a);
    s_q[g * 68 + e] = a * 8.0f;
  }
  __syncthreads();
  // qk: thread owns channel tid; w_k row contiguous (float4)
  {
    float acc[QTF];
    #pragma unroll
    for (int qs = 0; qs < QTF; qs++) acc[qs] = 0.f;
    const float4* wk4 = reinterpret_cast<const float4*>(w_k + (size_t)tid * EDIM);
    for (int e4 = 0; e4 < EDIM / 4; e4++) {
      float4 wv = wk4[e4];
      int e = e4 * 4;
      #pragma unroll
      for (int qs = 0; qs < QTF; qs++) {
        acc[qs] = fmaf(s_q[qs * 68 + e + 0], wv.x, acc[qs]);
        acc[qs] = fmaf(s_q[qs * 68 + e + 1], wv.y, acc[qs]);
        acc[qs] = fmaf(s_q[qs * 68 + e + 2], wv.z, acc[qs]);
        acc[qs] = fmaf(s_q[qs * 68 + e + 3], wv.w, acc[qs]);
      }
    }
    #pragma unroll
    for (int qs = 0; qs < QTF; qs++)
      qk[(size_t)(q0l + qs) * FD + tid] = acc[qs];
  }
}

// ---------------------------------------------------------------------------
// K3 (hot): ONE query per block, wave w -> head w. Head h only attends
// points p ≡ h (mod NH), so each wave samples exactly its 8 points.
// ROUND-3 CHANGE: round 2 showed attnk latency-bound at 16 waves/CU
// (grid 1024 = 4 blocks/CU cap; VALUBusy 12%, ~63 cyc per issued gather).
// Kernel needs only 52 VGPR + 2.7 KB LDS -> hardware allows 32 waves/CU.
// Supply them: grid 2048 blocks (8/CU), launch_bounds(256,8) caps VGPR at
// 64 so 8 waves/EU is reachable. Per-wave state (8 bf16x4 af + 8 sim) fits.
// ---------------------------------------------------------------------------
__global__ __launch_bounds__(256, 8) void attnk(
    const float* __restrict__ planesT, const float* __restrict__ aux,
    const float* __restrict__ qk, const unsigned* __restrict__ perm,
    float* __restrict__ wf)
{
  const int tid = threadIdx.x, lane = tid & 63, w = tid >> 6;
  const int bid = blockIdx.x;                 // 0..2047
  const int j = ((bid & 7) << 8) | (bid >> 3);  // XCD-chunked swizzle
  const int c4 = lane * 4;

  __shared__ int   s_si[96][3];
  __shared__ float s_sw[96][4];

  const int qw = (int)perm[j];                // this block's query (uniform)
  const int blw = qw >> 10;

  if (tid < 96) {
    int p = tid / 3, pl = tid - p * 3;
    float ax = aux[(size_t)qw * 96 + p * 3 + 0];
    float ay = aux[(size_t)qw * 96 + p * 3 + 1];
    float az = aux[(size_t)qw * 96 + p * 3 + 2];
    float u = (pl == 2) ? ay : ax;   // pl0:(ax,az) pl1:(ax,ay) pl2:(ay,az)
    float v = (pl == 1) ? ay : az;
    setup_samp(s_si[tid], s_sw[tid], u, v);
  }

  const int h = w;                            // wave = head
  float4 qk4 = *(const float4*)(qk + (size_t)qw * FD + c4);
  const float* P0 = planesT + 0 * (size_t)PPLANE + (size_t)blw * BATCH_ELEMS + c4;
  const float* P1 = planesT + 1 * (size_t)PPLANE + (size_t)blw * BATCH_ELEMS + c4;
  const float* P2 = planesT + 2 * (size_t)PPLANE + (size_t)blw * BATCH_ELEMS + c4;
  __syncthreads();

  ushort4 af16[SP3];                          // bf16 af, 16 VGPRs (static idx)
  float sim[SP3];                             // wave-uniform sims (static idx)
  #pragma unroll
  for (int jj = 0; jj < SP3; jj++) {
    const int p = jj * NH + h;
    float4 a; a.x = 0.f; a.y = 0.f; a.z = 0.f; a.w = 0.f;
    #pragma unroll
    for (int pl = 0; pl < 3; pl++) {
      const float* P = pl == 0 ? P0 : (pl == 1 ? P1 : P2);
      int i00 = s_si[p * 3 + pl][0];
      int dxo = s_si[p * 3 + pl][1];
      int dyo = s_si[p * 3 + pl][2];
      float w0 = s_sw[p * 3 + pl][0], w1 = s_sw[p * 3 + pl][1];
      float w2 = s_sw[p * 3 + pl][2], w3 = s_sw[p * 3 + pl][3];
      float4 f00 = *(const float4*)(P + i00);
      float4 f01 = *(const float4*)(P + i00 + dxo);
      float4 f10 = *(const float4*)(P + i00 + dyo);
      float4 f11 = *(const float4*)(P + i00 + dyo + dxo);
      a.x = fmaf(w0, f00.x, fmaf(w1, f01.x, fmaf(w2, f10.x, fmaf(w3, f11.x, a.x))));
      a.y = fmaf(w0, f00.y, fmaf(w1, f01.y, fmaf(w2, f10.y, fmaf(w3, f11.y, a.y))));
      a.z = fmaf(w0, f00.z, fmaf(w1, f01.z, fmaf(w2, f10.z, fmaf(w3, f11.z, a.z))));
      a.w = fmaf(w0, f00.w, fmaf(w1, f01.w, fmaf(w2, f10.w, fmaf(w3, f11.w, a.w))));
    }
    ushort4 hh;
    hh.x = f2bf(a.x); hh.y = f2bf(a.y); hh.z = f2bf(a.z); hh.w = f2bf(a.w);
    af16[jj] = hh;
    float t = fmaf(qk4.x, a.x, fmaf(qk4.y, a.y, fmaf(qk4.z, a.z, qk4.w * a.w)));
    #pragma unroll
    for (int o = 32; o >= 1; o >>= 1) t += __shfl_xor(t, o, 64);
    sim[jj] = t;                              // uniform across lanes
  }
  // softmax over jj (uniform scalar math in every lane; no LDS, no barrier)
  float m = -1e30f;
  #pragma unroll
  for (int jj = 0; jj < SP3; jj++) m = fmaxf(m, sim[jj]);
  float sum = 0.f;
  #pragma unroll
  for (int jj = 0; jj < SP3; jj++) { sim[jj] = __expf(sim[jj] - m); sum += sim[jj]; }
  float inv = 1.0f / sum;
  float4 r; r.x = 0.f; r.y = 0.f; r.z = 0.f; r.w = 0.f;
  #pragma unroll
  for (int jj = 0; jj < SP3; jj++) {
    float av = sim[jj] * inv;
    ushort4 hv = af16[jj];
    r.x = fmaf(av, bf2f(hv.x), r.x);
    r.y = fmaf(av, bf2f(hv.y), r.y);
    r.z = fmaf(av, bf2f(hv.z), r.z);
    r.w = fmaf(av, bf2f(hv.w), r.w);
  }
  *(float4*)(wf + ((size_t)qw * NH + h) * FD + c4) = r;
}

// ---------------------------------------------------------------------------
// K4: epilogue per 4-query tile: o = per-head wf@w_v + b_v (w_v in LDS),
// then out = o@w_out + b_out + feat (w_out streamed once per block).
// QTE=4 -> 512 blocks -> 2 blocks/CU (LDS 68 KB still allows 2).
// ---------------------------------------------------------------------------
__global__ __launch_bounds__(256) void epik(
    const float* __restrict__ wf, const float* __restrict__ feat,
    const float* __restrict__ w_v, const float* __restrict__ b_v,
    const float* __restrict__ w_out, const float* __restrict__ b_out,
    float* __restrict__ out, int b0)
{
  const int tid = threadIdx.x;
  const int q0l = blockIdx.x * QTE;
  __shared__ float s_wv[FD * EDIM];   // 64 KB, [c][e]
  __shared__ float s_o[QTE * 257];

  {
    const float4* src4 = (const float4*)w_v;
    float4* dst4 = (float4*)s_wv;
    #pragma unroll
    for (int i = 0; i < (FD * EDIM / 4) / 256; i++)
      dst4[tid + 256 * i] = src4[tid + 256 * i];
  }
  __syncthreads();

  { // phase A: o[qs][h*64+e]
    int h = tid >> 6, e = tid & 63;
    float acc[QTE];
    float bv = b_v[e];
    #pragma unroll
    for (int qs = 0; qs < QTE; qs++) acc[qs] = bv;
    const float* wrow = wf + ((size_t)q0l * NH + h) * FD;
    for (int c = 0; c < FD; c++) {
      float wv = s_wv[c * EDIM + e];
      #pragma unroll
      for (int qs = 0; qs < QTE; qs++)
        acc[qs] = fmaf(wrow[(size_t)qs * NH * FD + c], wv, acc[qs]);
    }
    #pragma unroll
    for (int qs = 0; qs < QTE; qs++) s_o[qs * 257 + h * EDIM + e] = acc[qs];
  }
  __syncthreads();

  { // phase B: out[q][d] = sum_c o[q][c] w_out[c][d] + b_out[d] + feat[q][d]
    float r[QTE];
    float bo = b_out[tid];
    #pragma unroll
    for (int qs = 0; qs < QTE; qs++) r[qs] = bo;
    for (int c = 0; c < FD; c++) {
      float wv = w_out[(size_t)c * FD + tid];
      #pragma unroll
      for (int qs = 0; qs < QTE; qs++)
        r[qs] = fmaf(s_o[qs * 257 + c], wv, r[qs]);
    }
    #pragma unroll
    for (int qs = 0; qs < QTE; qs++)
      out[((size_t)b0 * NS + q0l + qs) * FD + tid]
          = r[qs] + feat[(size_t)(q0l + qs) * FD + tid];
  }
}

// ---------------------------------------------------------------------------
extern "C" void kernel_launch(void* const* d_in, const int* in_sizes, int n_in,
                              void* d_out, int out_size, void* d_ws, size_t ws_size,
                              hipStream_t stream) {
  const float* qp    = (const float*)d_in[0];
  const float* cxz   = (const float*)d_in[1];
  const float* cxy   = (const float*)d_in[2];
  const float* cyz   = (const float*)d_in[3];
  const float* w_off = (const float*)d_in[4];
  const float* b_off = (const float*)d_in[5];
  const float* w_q   = (const float*)d_in[6];
  const float* b_q   = (const float*)d_in[7];
  const float* w_k   = (const float*)d_in[8];
  const float* b_k   = (const float*)d_in[9];   (void)b_k; // cancels in softmax
  const float* w_v   = (const float*)d_in[10];
  const float* b_v   = (const float*)d_in[11];
  const float* w_out = (const float*)d_in[12];
  const float* b_out = (const float*)d_in[13];
  float* out = (float*)d_out;
  (void)in_sizes; (void)n_in; (void)out_size; (void)ws_size;

  float* ws      = (float*)d_ws;
  float* planesT = ws + WS_PLANES;
  float* feat    = ws + WS_FEAT;
  float* qk      = ws + WS_QK;
  float* aux     = ws + WS_AUX;
  float* wf      = ws + WS_WF;
  unsigned* perm = (unsigned*)(ws + WS_PERM);

  hipLaunchKernelGGL(sortk, dim3(BS / PAIR_B), dim3(1024), 0, stream, qp, perm);

  for (int pair = 0; pair < BS / PAIR_B; ++pair) {
    int b0 = pair * PAIR_B;
    hipLaunchKernelGGL(tpk2, dim3(3 * PAIR_B * 512), dim3(256), 0, stream,
                       cxz, cxy, cyz, planesT, b0);
    hipLaunchKernelGGL(featk, dim3(PAIR_Q / QTF), dim3(256), 0, stream,
                       qp, planesT, w_off, b_off, w_q, b_q, w_k,
                       feat, aux, qk, b0);
    hipLaunchKernelGGL(attnk, dim3(PAIR_Q), dim3(256), 0, stream,
                       planesT, aux, qk, perm + (size_t)pair * PAIR_Q, wf);
    hipLaunchKernelGGL(epik, dim3(PAIR_Q / QTE), dim3(256), 0, stream,
                       wf, feat, w_v, b_v, w_out, b_out, out, b0);
  }
}

// Round 4
// 514.590 us; speedup vs baseline: 1.0098x; 1.0098x over previous
//
#include <hip/hip_runtime.h>
#include <math.h>

// Problem constants
#define FD   256
#define NH   4
#define SP3  8
#define NP   32          // SP3*NH aux points per query
#define EDIM 64          // FD/NH
#define H    128
#define NS   1024
#define BS   4
#define QTF  4           // queries per featk block (512 blocks -> 2/CU)
#define QTE  4           // queries per epik block  (512 blocks -> 2/CU)

#define TEX         (H*H)              // 16384 texels per (plane,b)
#define BATCH_ELEMS (TEX*FD)           // 4,194,304 floats
#define PAIR_B      2                  // batches processed per pass
#define PAIR_Q      (PAIR_B*NS)        // 2048 queries per pass
#define PPLANE      (PAIR_B*BATCH_ELEMS) // per-plane elems in pair buffer

// ---- workspace layout (float offsets). Total ~114.05 MB.
// ws_size proven >= 114 MB (rounds 3/5 passed); 228 MB overflowed (round 2).
#define WS_PLANES 0
#define WS_FEAT   (3*PPLANE)                       // [2048][256]
#define WS_QK     (WS_FEAT + PAIR_Q*FD)            // [2048][256]
#define WS_AUX    (WS_QK   + PAIR_Q*FD)            // [2048][96]
#define WS_WF     (WS_AUX  + PAIR_Q*NP*3)          // [2048][4][256]
#define WS_PERM   (WS_WF   + PAIR_Q*NH*FD)         // [2 pairs][2048] uint

// bf16 helpers (round-to-nearest-even). Used ONLY on the wf path (af after
// the fp32 sim dot) — sim-path quantization is amplified ~176x and is fatal.
__device__ __forceinline__ unsigned short f2bf(float f) {
  unsigned b = __float_as_uint(f);
  return (unsigned short)((b + 0x7FFFu + ((b >> 16) & 1u)) >> 16);
}
__device__ __forceinline__ float bf2f(unsigned short u) {
  return __uint_as_float(((unsigned)u) << 16);
}

// ---------------------------------------------------------------------------
// K1: transpose planes [B,C,H,W] -> [b-pair][H*W,C] (channel-last).
// 32-texel x 256-channel tiles; LDS 33 KB -> 4 blocks/CU.
// ---------------------------------------------------------------------------
__global__ __launch_bounds__(256) void tpk2(
    const float* __restrict__ xz, const float* __restrict__ xy,
    const float* __restrict__ yz, float* __restrict__ dstAll, int b0)
{
  int bid = blockIdx.x;
  int tT = bid & 511; bid >>= 9;     // 512 texel-tiles of 32
  int bl = bid & 1;   bid >>= 1;     // local batch in pair
  int pl = bid;                      // plane
  const float* src = pl == 0 ? xz : (pl == 1 ? xy : yz);
  float* dst = dstAll + (size_t)pl * PPLANE + (size_t)bl * BATCH_ELEMS;
  int b = b0 + bl;

  __shared__ float T[32 * 260];      // T[texel][channel], stride 260
  int lane = threadIdx.x & 63, w = threadIdx.x >> 6;
  int tex4 = (lane & 7) * 4;         // 0,4,..,28
  int csub = lane >> 3;              // 0..7

  const float* sbase = src + (size_t)b * FD * TEX + tT * 32;
  #pragma unroll
  for (int i = 0; i < 8; i++) {
    int c = i * 32 + w * 8 + csub;   // covers 0..255
    float4 v = *(const float4*)(sbase + (size_t)c * TEX + tex4);
    T[(tex4 + 0) * 260 + c] = v.x;
    T[(tex4 + 1) * 260 + c] = v.y;
    T[(tex4 + 2) * 260 + c] = v.z;
    T[(tex4 + 3) * 260 + c] = v.w;
  }
  __syncthreads();
  #pragma unroll
  for (int i = 0; i < 8; i++) {
    int t = w * 8 + i;
    float4 v = *(const float4*)(&T[t * 260 + lane * 4]);
    *(float4*)(dst + (size_t)(tT * 32 + t) * FD + lane * 4) = v;  // 1KB/wave
  }
}

// ---------------------------------------------------------------------------
// K1b: counting-sort the pair's 2048 queries into 256 buckets =
// (batch<<7)|top-7-Morton-bits. Any permutation is correctness-neutral;
// bucket granularity (~8 queries/cell) is all the locality we measured to
// matter. One block per pair, O(n), ~3 barriers.
// ---------------------------------------------------------------------------
__device__ __forceinline__ unsigned mort7(unsigned v) {   // 7 bits -> every 3rd
  unsigned r = 0;
  #pragma unroll
  for (int i = 0; i < 7; i++) r |= ((v >> i) & 1u) << (3 * i);
  return r;
}

__global__ __launch_bounds__(1024) void sortk(
    const float* __restrict__ qpos, unsigned* __restrict__ perm)
{
  const int pair = blockIdx.x;
  const int b0 = pair * PAIR_B;
  const int t = threadIdx.x;
  __shared__ unsigned cnt[256];
  __shared__ unsigned base[256];
  if (t < 256) cnt[t] = 0;
  __syncthreads();
  unsigned myb[2];
  #pragma unroll
  for (int r = 0; r < 2; r++) {
    int i = t + r * 1024;
    size_t qg = (size_t)b0 * NS + i;
    float x = fminf(fmaxf(qpos[qg * 3 + 0], 0.f), 1.f);
    float y = fminf(fmaxf(qpos[qg * 3 + 1], 0.f), 1.f);
    float z = fminf(fmaxf(qpos[qg * 3 + 2], 0.f), 1.f);
    unsigned m = (mort7((unsigned)(x * 127.f)) << 2)
               | (mort7((unsigned)(y * 127.f)) << 1)
               |  mort7((unsigned)(z * 127.f));          // 21 bits
    unsigned bkt = ((unsigned)(i >> 10) << 7) | (m >> 14);
    myb[r] = bkt;
    atomicAdd(&cnt[bkt], 1u);
  }
  __syncthreads();
  if (t == 0) {
    unsigned s = 0;
    for (int k = 0; k < 256; k++) { base[k] = s; s += cnt[k]; }
  }
  __syncthreads();
  #pragma unroll
  for (int r = 0; r < 2; r++) {
    int i = t + r * 1024;
    unsigned pos = atomicAdd(&base[myb[r]], 1u);
    perm[(size_t)pair * PAIR_Q + pos] = (unsigned)i;
  }
}

// ---------------------------------------------------------------------------
// Bilinear helpers (channel-last plane)
// ---------------------------------------------------------------------------
__device__ __forceinline__ float sample_plane(const float* __restrict__ p,
                                              float u, float v) {
  float x = fminf(fmaxf(u, 0.f), 1.f) * (float)(H - 1);
  float y = fminf(fmaxf(v, 0.f), 1.f) * (float)(H - 1);
  float xf = floorf(x), yf = floorf(y);
  int x0 = (int)xf, y0 = (int)yf;
  float wx = x - xf, wy = y - yf;
  int dx = (x0 < H - 1) ? FD : 0;
  int dy = (y0 < H - 1) ? H * FD : 0;
  int i00 = (y0 * H + x0) * FD;
  float f00 = p[i00], f01 = p[i00 + dx], f10 = p[i00 + dy], f11 = p[i00 + dy + dx];
  float a = f00 + wx * (f01 - f00);
  float b = f10 + wx * (f11 - f10);
  return a + wy * (b - a);
}

__device__ __forceinline__ void setup_samp(int* si, float* sw, float u, float v) {
  float x = fminf(fmaxf(u, 0.f), 1.f) * (float)(H - 1);
  float y = fminf(fmaxf(v, 0.f), 1.f) * (float)(H - 1);
  float xf = floorf(x), yf = floorf(y);
  int x0 = (int)xf, y0 = (int)yf;
  float wx = x - xf, wy = y - yf;
  si[0] = (y0 * H + x0) * FD;
  si[1] = (x0 < H - 1) ? FD : 0;
  si[2] = (y0 < H - 1) ? H * FD : 0;
  sw[0] = (1.f - wy) * (1.f - wx);
  sw[1] = (1.f - wy) * wx;
  sw[2] = wy * (1.f - wx);
  sw[3] = wy * wx;
}

// ---------------------------------------------------------------------------
// K2: per 4-query tile: feature sampling + offsets/aux + q-projection + qk.
// qk[q][c] = sum_e q_scaled[e] * w_k[c][e];  (q . b_k cancels in softmax)
// QTF=4 -> 512 blocks -> 2 blocks/CU (was 1/CU at QT=8: latency-exposed).
// ---------------------------------------------------------------------------
__global__ __launch_bounds__(256) void featk(
    const float* __restrict__ qpos, const float* __restrict__ planesT,
    const float* __restrict__ w_off, const float* __restrict__ b_off,
    const float* __restrict__ w_q, const float* __restrict__ b_q,
    const float* __restrict__ w_k,
    float* __restrict__ feat, float* __restrict__ aux, float* __restrict__ qk,
    int b0)
{
  const int tid = threadIdx.x;
  const int q0l = blockIdx.x * QTF;         // local query base in pair
  const int bl = q0l >> 10;                 // local batch
  __shared__ float s_feat[QTF * 260];
  __shared__ float s_q[QTF * 68];

  const float* Pxz = planesT + 0 * (size_t)PPLANE + (size_t)bl * BATCH_ELEMS + tid;
  const float* Pxy = planesT + 1 * (size_t)PPLANE + (size_t)bl * BATCH_ELEMS + tid;
  const float* Pyz = planesT + 2 * (size_t)PPLANE + (size_t)bl * BATCH_ELEMS + tid;

  for (int qs = 0; qs < QTF; qs++) {
    size_t qg = (size_t)b0 * NS + q0l + qs; // global query for qpos
    float px = qpos[qg * 3 + 0], py = qpos[qg * 3 + 1], pz = qpos[qg * 3 + 2];
    float f = sample_plane(Pxz, px, pz) + sample_plane(Pxy, px, py)
            + sample_plane(Pyz, py, pz);
    s_feat[qs * 260 + tid] = f;
    feat[(size_t)(q0l + qs) * FD + tid] = f;
  }
  __syncthreads();

  // offsets -> aux. thread t<192: half=t/96 handles 2 queries for column j.
  if (tid < 192) {
    int half = tid / 96, j = tid - half * 96;
    float acc[2];
    float bj = b_off[j];
    acc[0] = bj; acc[1] = bj;
    for (int c = 0; c < FD; c++) {
      float wv = w_off[c * 96 + j];
      #pragma unroll
      for (int k = 0; k < 2; k++)
        acc[k] = fmaf(s_feat[(half * 2 + k) * 260 + c], wv, acc[k]);
    }
    int d = j % 3;
    #pragma unroll
    for (int k = 0; k < 2; k++) {
      int qs = half * 2 + k;
      size_t qg = (size_t)b0 * NS + q0l + qs;
      aux[(size_t)(q0l + qs) * 96 + j] = acc[k] + qpos[qg * 3 + d];
    }
  }
  // q projection (scaled by sqrt(E)=8); wave g handles query g
  {
    int e = tid & 63, g = tid >> 6;
    float a = b_q[e];
    for (int c = 0; c < FD; c++)
      a = fmaf(s_feat[g * 260 + c], w_q[c * EDIM + e], a);
    s_q[g * 68 + e] = a * 8.0f;
  }
  __syncthreads();
  // qk: thread owns channel tid; w_k row contiguous (float4)
  {
    float acc[QTF];
    #pragma unroll
    for (int qs = 0; qs < QTF; qs++) acc[qs] = 0.f;
    const float4* wk4 = reinterpret_cast<const float4*>(w_k + (size_t)tid * EDIM);
    for (int e4 = 0; e4 < EDIM / 4; e4++) {
      float4 wv = wk4[e4];
      int e = e4 * 4;
      #pragma unroll
      for (int qs = 0; qs < QTF; qs++) {
        acc[qs] = fmaf(s_q[qs * 68 + e + 0], wv.x, acc[qs]);
        acc[qs] = fmaf(s_q[qs * 68 + e + 1], wv.y, acc[qs]);
        acc[qs] = fmaf(s_q[qs * 68 + e + 2], wv.z, acc[qs]);
        acc[qs] = fmaf(s_q[qs * 68 + e + 3], wv.w, acc[qs]);
      }
    }
    #pragma unroll
    for (int qs = 0; qs < QTF; qs++)
      qk[(size_t)(q0l + qs) * FD + tid] = acc[qs];
  }
}

// ---------------------------------------------------------------------------
// K3 (hot): ONE query per block, wave w -> head w (head h attends points
// p ≡ h mod NH). ROUND-4 CHANGE: explicit 2-deep ping-pong software pipeline
// over the 24 plane-quads (8 points x 3 planes): issue quad k+1's 4 corner
// loads before consuming quad k. Shuffle-reduce hoisted OUT of the gather
// loop (8 independent butterfly chains at the end) so no per-point
// serialization. Rationale: r2 (16 waves, VGPR 52) == r3 (32 waves, VGPR 32)
// == ~82 us -> aggregate in-flight loads/CU was constant (~50 lines, Little's
// law at 600cy). This config targets 24 waves/CU x ~5 in flight = 2.4x
// aggregate MLP. launch_bounds(256,6): VGPR cap ~85, pipeline needs ~80.
// If flat again -> throughput wall confirmed -> switch to traffic reduction.
// ---------------------------------------------------------------------------
__global__ __launch_bounds__(256, 6) void attnk(
    const float* __restrict__ planesT, const float* __restrict__ aux,
    const float* __restrict__ qk, const unsigned* __restrict__ perm,
    float* __restrict__ wf)
{
  const int tid = threadIdx.x, lane = tid & 63, w = tid >> 6;
  const int bid = blockIdx.x;                 // 0..2047
  const int j = ((bid & 7) << 8) | (bid >> 3);  // XCD-chunked swizzle
  const int c4 = lane * 4;

  __shared__ int   s_si[96][3];
  __shared__ float s_sw[96][4];

  const int qw = (int)perm[j];                // this block's query (uniform)
  const int blw = qw >> 10;

  if (tid < 96) {
    int p = tid / 3, pl = tid - p * 3;
    float ax = aux[(size_t)qw * 96 + p * 3 + 0];
    float ay = aux[(size_t)qw * 96 + p * 3 + 1];
    float az = aux[(size_t)qw * 96 + p * 3 + 2];
    float u = (pl == 2) ? ay : ax;   // pl0:(ax,az) pl1:(ax,ay) pl2:(ay,az)
    float v = (pl == 1) ? ay : az;
    setup_samp(s_si[tid], s_sw[tid], u, v);
  }

  const int h = w;                            // wave = head
  float4 qk4 = *(const float4*)(qk + (size_t)qw * FD + c4);
  const float* P0 = planesT + 0 * (size_t)PPLANE + (size_t)blw * BATCH_ELEMS + c4;
  const float* P1 = planesT + 1 * (size_t)PPLANE + (size_t)blw * BATCH_ELEMS + c4;
  const float* P2 = planesT + 2 * (size_t)PPLANE + (size_t)blw * BATCH_ELEMS + c4;
  __syncthreads();

  ushort4 af16[SP3];                          // bf16 af (static idx)
  float t[SP3];                               // per-lane sim partials
  float4 acc;                                 // current point's af accumulator

  float4 bA00, bA01, bA10, bA11;              // ping buffer
  float4 bB00, bB01, bB10, bB11;              // pong buffer

  // issue quad k's 4 corner loads into a buffer (k = point*3 + plane)
  auto issue = [&](int k, float4& b00, float4& b01, float4& b10, float4& b11) {
    const int pl = k % 3;
    const int p  = (k / 3) * NH + h;
    const float* P = pl == 0 ? P0 : (pl == 1 ? P1 : P2);
    int i00 = s_si[p * 3 + pl][0];
    int dxo = s_si[p * 3 + pl][1];
    int dyo = s_si[p * 3 + pl][2];
    b00 = *(const float4*)(P + i00);
    b01 = *(const float4*)(P + i00 + dxo);
    b10 = *(const float4*)(P + i00 + dyo);
    b11 = *(const float4*)(P + i00 + dyo + dxo);
  };
  // consume quad k: weighted-accumulate into acc; finalize point at pl==2
  auto consume = [&](int k, float4& b00, float4& b01, float4& b10, float4& b11) {
    const int pl = k % 3, jj = k / 3;
    const int p  = jj * NH + h;
    float w0 = s_sw[p * 3 + pl][0], w1 = s_sw[p * 3 + pl][1];
    float w2 = s_sw[p * 3 + pl][2], w3 = s_sw[p * 3 + pl][3];
    if (pl == 0) { acc.x = 0.f; acc.y = 0.f; acc.z = 0.f; acc.w = 0.f; }
    acc.x = fmaf(w0, b00.x, fmaf(w1, b01.x, fmaf(w2, b10.x, fmaf(w3, b11.x, acc.x))));
    acc.y = fmaf(w0, b00.y, fmaf(w1, b01.y, fmaf(w2, b10.y, fmaf(w3, b11.y, acc.y))));
    acc.z = fmaf(w0, b00.z, fmaf(w1, b01.z, fmaf(w2, b10.z, fmaf(w3, b11.z, acc.z))));
    acc.w = fmaf(w0, b00.w, fmaf(w1, b01.w, fmaf(w2, b10.w, fmaf(w3, b11.w, acc.w))));
    if (pl == 2) {
      ushort4 hh;
      hh.x = f2bf(acc.x); hh.y = f2bf(acc.y); hh.z = f2bf(acc.z); hh.w = f2bf(acc.w);
      af16[jj] = hh;
      t[jj] = fmaf(qk4.x, acc.x, fmaf(qk4.y, acc.y, fmaf(qk4.z, acc.z, qk4.w * acc.w)));
    }
  };

  issue(0, bA00, bA01, bA10, bA11);
  #pragma unroll
  for (int k = 0; k < 24; k += 2) {
    if (k + 1 < 24) issue(k + 1, bB00, bB01, bB10, bB11);
    consume(k, bA00, bA01, bA10, bA11);
    if (k + 2 < 24) issue(k + 2, bA00, bA01, bA10, bA11);
    if (k + 1 < 24) consume(k + 1, bB00, bB01, bB10, bB11);
  }

  // wave-reduce all 8 sims together: 8 independent butterfly chains
  #pragma unroll
  for (int o = 32; o >= 1; o >>= 1) {
    #pragma unroll
    for (int jj = 0; jj < SP3; jj++) t[jj] += __shfl_xor(t[jj], o, 64);
  }

  // softmax over jj (uniform scalar math in every lane; no LDS, no barrier)
  float m = -1e30f;
  #pragma unroll
  for (int jj = 0; jj < SP3; jj++) m = fmaxf(m, t[jj]);
  float sum = 0.f;
  #pragma unroll
  for (int jj = 0; jj < SP3; jj++) { t[jj] = __expf(t[jj] - m); sum += t[jj]; }
  float inv = 1.0f / sum;
  float4 r; r.x = 0.f; r.y = 0.f; r.z = 0.f; r.w = 0.f;
  #pragma unroll
  for (int jj = 0; jj < SP3; jj++) {
    float av = t[jj] * inv;
    ushort4 hv = af16[jj];
    r.x = fmaf(av, bf2f(hv.x), r.x);
    r.y = fmaf(av, bf2f(hv.y), r.y);
    r.z = fmaf(av, bf2f(hv.z), r.z);
    r.w = fmaf(av, bf2f(hv.w), r.w);
  }
  *(float4*)(wf + ((size_t)qw * NH + h) * FD + c4) = r;
}

// ---------------------------------------------------------------------------
// K4: epilogue per 4-query tile: o = per-head wf@w_v + b_v (w_v in LDS),
// then out = o@w_out + b_out + feat (w_out streamed once per block).
// QTE=4 -> 512 blocks -> 2 blocks/CU (LDS 68 KB still allows 2).
// ---------------------------------------------------------------------------
__global__ __launch_bounds__(256) void epik(
    const float* __restrict__ wf, const float* __restrict__ feat,
    const float* __restrict__ w_v, const float* __restrict__ b_v,
    const float* __restrict__ w_out, const float* __restrict__ b_out,
    float* __restrict__ out, int b0)
{
  const int tid = threadIdx.x;
  const int q0l = blockIdx.x * QTE;
  __shared__ float s_wv[FD * EDIM];   // 64 KB, [c][e]
  __shared__ float s_o[QTE * 257];

  {
    const float4* src4 = (const float4*)w_v;
    float4* dst4 = (float4*)s_wv;
    #pragma unroll
    for (int i = 0; i < (FD * EDIM / 4) / 256; i++)
      dst4[tid + 256 * i] = src4[tid + 256 * i];
  }
  __syncthreads();

  { // phase A: o[qs][h*64+e]
    int h = tid >> 6, e = tid & 63;
    float acc[QTE];
    float bv = b_v[e];
    #pragma unroll
    for (int qs = 0; qs < QTE; qs++) acc[qs] = bv;
    const float* wrow = wf + ((size_t)q0l * NH + h) * FD;
    for (int c = 0; c < FD; c++) {
      float wv = s_wv[c * EDIM + e];
      #pragma unroll
      for (int qs = 0; qs < QTE; qs++)
        acc[qs] = fmaf(wrow[(size_t)qs * NH * FD + c], wv, acc[qs]);
    }
    #pragma unroll
    for (int qs = 0; qs < QTE; qs++) s_o[qs * 257 + h * EDIM + e] = acc[qs];
  }
  __syncthreads();

  { // phase B: out[q][d] = sum_c o[q][c] w_out[c][d] + b_out[d] + feat[q][d]
    float r[QTE];
    float bo = b_out[tid];
    #pragma unroll
    for (int qs = 0; qs < QTE; qs++) r[qs] = bo;
    for (int c = 0; c < FD; c++) {
      float wv = w_out[(size_t)c * FD + tid];
      #pragma unroll
      for (int qs = 0; qs < QTE; qs++)
        r[qs] = fmaf(s_o[qs * 257 + c], wv, r[qs]);
    }
    #pragma unroll
    for (int qs = 0; qs < QTE; qs++)
      out[((size_t)b0 * NS + q0l + qs) * FD + tid]
          = r[qs] + feat[(size_t)(q0l + qs) * FD + tid];
  }
}

// ---------------------------------------------------------------------------
extern "C" void kernel_launch(void* const* d_in, const int* in_sizes, int n_in,
                              void* d_out, int out_size, void* d_ws, size_t ws_size,
                              hipStream_t stream) {
  const float* qp    = (const float*)d_in[0];
  const float* cxz   = (const float*)d_in[1];
  const float* cxy   = (const float*)d_in[2];
  const float* cyz   = (const float*)d_in[3];
  const float* w_off = (const float*)d_in[4];
  const float* b_off = (const float*)d_in[5];
  const float* w_q   = (const float*)d_in[6];
  const float* b_q   = (const float*)d_in[7];
  const float* w_k   = (const float*)d_in[8];
  const float* b_k   = (const float*)d_in[9];   (void)b_k; // cancels in softmax
  const float* w_v   = (const float*)d_in[10];
  const float* b_v   = (const float*)d_in[11];
  const float* w_out = (const float*)d_in[12];
  const float* b_out = (const float*)d_in[13];
  float* out = (float*)d_out;
  (void)in_sizes; (void)n_in; (void)out_size; (void)ws_size;

  float* ws      = (float*)d_ws;
  float* planesT = ws + WS_PLANES;
  float* feat    = ws + WS_FEAT;
  float* qk      = ws + WS_QK;
  float* aux     = ws + WS_AUX;
  float* wf      = ws + WS_WF;
  unsigned* perm = (unsigned*)(ws + WS_PERM);

  hipLaunchKernelGGL(sortk, dim3(BS / PAIR_B), dim3(1024), 0, stream, qp, perm);

  for (int pair = 0; pair < BS / PAIR_B; ++pair) {
    int b0 = pair * PAIR_B;
    hipLaunchKernelGGL(tpk2, dim3(3 * PAIR_B * 512), dim3(256), 0, stream,
                       cxz, cxy, cyz, planesT, b0);
    hipLaunchKernelGGL(featk, dim3(PAIR_Q / QTF), dim3(256), 0, stream,
                       qp, planesT, w_off, b_off, w_q, b_q, w_k,
                       feat, aux, qk, b0);
    hipLaunchKernelGGL(attnk, dim3(PAIR_Q), dim3(256), 0, stream,
                       planesT, aux, qk, perm + (size_t)pair * PAIR_Q, wf);
    hipLaunchKernelGGL(epik, dim3(PAIR_Q / QTE), dim3(256), 0, stream,
                       wf, feat, w_v, b_v, w_out, b_out, out, b0);
  }
}

// Round 5
// 485.428 us; speedup vs baseline: 1.0704x; 1.0601x over previous
//
#include <hip/hip_runtime.h>
#include <math.h>

// Problem constants
#define FD   256
#define NH   4
#define SP3  8
#define NP   32          // SP3*NH aux points per query
#define EDIM 64          // FD/NH
#define H    128
#define NS   1024
#define BS   4

#define TEX         (H*H)              // 16384 texels per (plane,b)
#define BATCH_ELEMS (TEX*FD)           // 4,194,304 floats
#define PAIR_B      2                  // batches processed per pass
#define PAIR_Q      (PAIR_B*NS)        // 2048 queries per pass
#define PPLANE      (PAIR_B*BATCH_ELEMS) // per-plane elems in pair buffer

// ---- workspace layout (float offsets). Total ~114.05 MB (layout kept from
// the proven rounds; feat/qk/aux/wf slots now unused after fusion).
#define WS_PLANES 0
#define WS_FEAT   (3*PPLANE)                       // [2048][256] (unused)
#define WS_QK     (WS_FEAT + PAIR_Q*FD)            // [2048][256] (unused)
#define WS_AUX    (WS_QK   + PAIR_Q*FD)            // [2048][96]  (unused)
#define WS_WF     (WS_AUX  + PAIR_Q*NP*3)          // [2048][4][256] (unused)
#define WS_PERM   (WS_WF   + PAIR_Q*NH*FD)         // [2 pairs][2048] uint

// bf16 helpers (round-to-nearest-even). Used ONLY on the wf path (af after
// the fp32 sim dot) — sim-path quantization is amplified ~176x and is fatal.
__device__ __forceinline__ unsigned short f2bf(float f) {
  unsigned b = __float_as_uint(f);
  return (unsigned short)((b + 0x7FFFu + ((b >> 16) & 1u)) >> 16);
}
__device__ __forceinline__ float bf2f(unsigned short u) {
  return __uint_as_float(((unsigned)u) << 16);
}

// ---------------------------------------------------------------------------
// K1: transpose planes [B,C,H,W] -> [b-pair][H*W,C] (channel-last).
// 32-texel x 256-channel tiles; LDS 33 KB -> 4 blocks/CU.
// ---------------------------------------------------------------------------
__global__ __launch_bounds__(256) void tpk2(
    const float* __restrict__ xz, const float* __restrict__ xy,
    const float* __restrict__ yz, float* __restrict__ dstAll, int b0)
{
  int bid = blockIdx.x;
  int tT = bid & 511; bid >>= 9;     // 512 texel-tiles of 32
  int bl = bid & 1;   bid >>= 1;     // local batch in pair
  int pl = bid;                      // plane
  const float* src = pl == 0 ? xz : (pl == 1 ? xy : yz);
  float* dst = dstAll + (size_t)pl * PPLANE + (size_t)bl * BATCH_ELEMS;
  int b = b0 + bl;

  __shared__ float T[32 * 260];      // T[texel][channel], stride 260
  int lane = threadIdx.x & 63, w = threadIdx.x >> 6;
  int tex4 = (lane & 7) * 4;         // 0,4,..,28
  int csub = lane >> 3;              // 0..7

  const float* sbase = src + (size_t)b * FD * TEX + tT * 32;
  #pragma unroll
  for (int i = 0; i < 8; i++) {
    int c = i * 32 + w * 8 + csub;   // covers 0..255
    float4 v = *(const float4*)(sbase + (size_t)c * TEX + tex4);
    T[(tex4 + 0) * 260 + c] = v.x;
    T[(tex4 + 1) * 260 + c] = v.y;
    T[(tex4 + 2) * 260 + c] = v.z;
    T[(tex4 + 3) * 260 + c] = v.w;
  }
  __syncthreads();
  #pragma unroll
  for (int i = 0; i < 8; i++) {
    int t = w * 8 + i;
    float4 v = *(const float4*)(&T[t * 260 + lane * 4]);
    *(float4*)(dst + (size_t)(tT * 32 + t) * FD + lane * 4) = v;  // 1KB/wave
  }
}

// ---------------------------------------------------------------------------
// K1b: counting-sort the pair's 2048 queries into 256 buckets =
// (batch<<7)|top-7-Morton-bits. One block per pair, O(n).
// ---------------------------------------------------------------------------
__device__ __forceinline__ unsigned mort7(unsigned v) {   // 7 bits -> every 3rd
  unsigned r = 0;
  #pragma unroll
  for (int i = 0; i < 7; i++) r |= ((v >> i) & 1u) << (3 * i);
  return r;
}

__global__ __launch_bounds__(1024) void sortk(
    const float* __restrict__ qpos, unsigned* __restrict__ perm)
{
  const int pair = blockIdx.x;
  const int b0 = pair * PAIR_B;
  const int t = threadIdx.x;
  __shared__ unsigned cnt[256];
  __shared__ unsigned base[256];
  if (t < 256) cnt[t] = 0;
  __syncthreads();
  unsigned myb[2];
  #pragma unroll
  for (int r = 0; r < 2; r++) {
    int i = t + r * 1024;
    size_t qg = (size_t)b0 * NS + i;
    float x = fminf(fmaxf(qpos[qg * 3 + 0], 0.f), 1.f);
    float y = fminf(fmaxf(qpos[qg * 3 + 1], 0.f), 1.f);
    float z = fminf(fmaxf(qpos[qg * 3 + 2], 0.f), 1.f);
    unsigned m = (mort7((unsigned)(x * 127.f)) << 2)
               | (mort7((unsigned)(y * 127.f)) << 1)
               |  mort7((unsigned)(z * 127.f));          // 21 bits
    unsigned bkt = ((unsigned)(i >> 10) << 7) | (m >> 14);
    myb[r] = bkt;
    atomicAdd(&cnt[bkt], 1u);
  }
  __syncthreads();
  if (t == 0) {
    unsigned s = 0;
    for (int k = 0; k < 256; k++) { base[k] = s; s += cnt[k]; }
  }
  __syncthreads();
  #pragma unroll
  for (int r = 0; r < 2; r++) {
    int i = t + r * 1024;
    unsigned pos = atomicAdd(&base[myb[r]], 1u);
    perm[(size_t)pair * PAIR_Q + pos] = (unsigned)i;
  }
}

// ---------------------------------------------------------------------------
// Bilinear helpers (channel-last plane)
// ---------------------------------------------------------------------------
__device__ __forceinline__ float sample_plane(const float* __restrict__ p,
                                              float u, float v) {
  float x = fminf(fmaxf(u, 0.f), 1.f) * (float)(H - 1);
  float y = fminf(fmaxf(v, 0.f), 1.f) * (float)(H - 1);
  float xf = floorf(x), yf = floorf(y);
  int x0 = (int)xf, y0 = (int)yf;
  float wx = x - xf, wy = y - yf;
  int dx = (x0 < H - 1) ? FD : 0;
  int dy = (y0 < H - 1) ? H * FD : 0;
  int i00 = (y0 * H + x0) * FD;
  float f00 = p[i00], f01 = p[i00 + dx], f10 = p[i00 + dy], f11 = p[i00 + dy + dx];
  float a = f00 + wx * (f01 - f00);
  float b = f10 + wx * (f11 - f10);
  return a + wy * (b - a);
}

__device__ __forceinline__ void setup_samp(int* si, float* sw, float u, float v) {
  float x = fminf(fmaxf(u, 0.f), 1.f) * (float)(H - 1);
  float y = fminf(fmaxf(v, 0.f), 1.f) * (float)(H - 1);
  float xf = floorf(x), yf = floorf(y);
  int x0 = (int)xf, y0 = (int)yf;
  float wx = x - xf, wy = y - yf;
  si[0] = (y0 * H + x0) * FD;
  si[1] = (x0 < H - 1) ? FD : 0;
  si[2] = (y0 < H - 1) ? H * FD : 0;
  sw[0] = (1.f - wy) * (1.f - wx);
  sw[1] = (1.f - wy) * wx;
  sw[2] = wy * (1.f - wx);
  sw[3] = wy * wx;
}

// ---------------------------------------------------------------------------
// K3 (FUSED, hot): one query per block; featk + attnk + epik in one kernel.
// Rationale (r2/r3/r4 evidence): the gather phase saturates the fetch path at
// ~3.45 TB/s with VALUBusy only 13% — occupancy/ILP knobs are all flat. So
// the featk/epik dot-product work (previously ~100+ us of serialized wall
// time in separate launches) is moved INTO this kernel where it hides under
// the memory wall in other blocks' gather shadows. All FP accumulation
// orders are kept identical to the previously-passing kernels (absmax must
// stay 0.1279297).
// Stages: 1) feature sample (thread=channel, coalesced)
//         2) unified 256-dot: tid<96 offset col j; tid in[96,160) q-proj
//         3) qk[c] dot (all threads) + setup_samp (tid<96)
//         4) r4's pipelined gather + wave-uniform softmax (qk from LDS)
//         5) epilogue: o = wf@w_v + b_v; out = o@w_out + b_out + feat
// LDS ~10.3 KB; launch_bounds(256,8) -> 8 blocks/CU.
// ---------------------------------------------------------------------------
__global__ __launch_bounds__(256, 8) void fusedk(
    const float* __restrict__ qpos, const float* __restrict__ planesT,
    const float* __restrict__ w_off, const float* __restrict__ b_off,
    const float* __restrict__ w_q, const float* __restrict__ b_q,
    const float* __restrict__ w_k,
    const float* __restrict__ w_v, const float* __restrict__ b_v,
    const float* __restrict__ w_out, const float* __restrict__ b_out,
    const unsigned* __restrict__ perm, float* __restrict__ out, int b0)
{
  const int tid = threadIdx.x, lane = tid & 63, w = tid >> 6;
  const int bid = blockIdx.x;                 // 0..2047
  const int j = ((bid & 7) << 8) | (bid >> 3);  // XCD-chunked swizzle
  const int c4 = lane * 4;

  __shared__ float s_feat[FD];        // 1 KB   (query feature; lives to stage5)
  __shared__ float s_aux[96];         // aux coords
  __shared__ float s_q[EDIM];         // scaled q
  __shared__ float s_qk[FD];          // qk row
  __shared__ int   s_si[96][3];
  __shared__ float s_sw[96][4];
  __shared__ float s_wf[NH * FD];     // 4 KB   (per-head attn output)
  __shared__ float s_o[FD];           // o = concat-head @ w_v

  const int qw = (int)perm[j];                // this block's query (uniform)
  const int blw = qw >> 10;
  const size_t qg = (size_t)b0 * NS + qw;     // global query row
  const float px = qpos[qg * 3 + 0];
  const float py = qpos[qg * 3 + 1];
  const float pz = qpos[qg * 3 + 2];

  const float* Pxz = planesT + 0 * (size_t)PPLANE + (size_t)blw * BATCH_ELEMS;
  const float* Pxy = planesT + 1 * (size_t)PPLANE + (size_t)blw * BATCH_ELEMS;
  const float* Pyz = planesT + 2 * (size_t)PPLANE + (size_t)blw * BATCH_ELEMS;

  // ---- stage 1: feature at query pos (thread = channel; same op order as featk)
  {
    float f = sample_plane(Pxz + tid, px, pz) + sample_plane(Pxy + tid, px, py)
            + sample_plane(Pyz + tid, py, pz);
    s_feat[tid] = f;
  }
  __syncthreads();

  // ---- stage 2: unified 256-dot. Uniform loop body (no divergence inside),
  // divergent only in base pointer/stride/bias.
  if (tid < 160) {
    const bool isOff = tid < 96;
    const int  col   = isOff ? tid : (tid - 96);
    const float* Wp  = isOff ? (w_off + col) : (w_q + col);
    const int  strd  = isOff ? 96 : EDIM;
    float acc = isOff ? b_off[col] : b_q[col];
    for (int c = 0; c < FD; c++) {
      acc = fmaf(s_feat[c], *Wp, acc);
      Wp += strd;
    }
    if (isOff) {
      int d = col % 3;
      float qp = (d == 0) ? px : ((d == 1) ? py : pz);
      s_aux[col] = acc + qp;
    } else {
      s_q[col] = acc * 8.0f;          // scaled by sqrt(E)=8 (b_k cancels)
    }
  }
  __syncthreads();

  // ---- stage 3: qk[c] (all 256 threads) + setup_samp (tid<96)
  {
    float acc = 0.f;
    const float* wk = w_k + (size_t)tid * EDIM;
    for (int e = 0; e < EDIM; e++)
      acc = fmaf(s_q[e], wk[e], acc);  // e ascending == featk's float4 order
    s_qk[tid] = acc;
  }
  if (tid < 96) {
    int p = tid / 3, pl = tid - p * 3;
    float ax = s_aux[p * 3 + 0];
    float ay = s_aux[p * 3 + 1];
    float az = s_aux[p * 3 + 2];
    float u = (pl == 2) ? ay : ax;   // pl0:(ax,az) pl1:(ax,ay) pl2:(ay,az)
    float v = (pl == 1) ? ay : az;
    setup_samp(s_si[tid], s_sw[tid], u, v);
  }
  __syncthreads();

  // ---- stage 4: pipelined gather + wave-uniform softmax (r4 core).
  const int h = w;                            // wave = head
  float4 qk4 = *(const float4*)(s_qk + c4);
  const float* P0 = Pxz + c4;
  const float* P1 = Pxy + c4;
  const float* P2 = Pyz + c4;

  ushort4 af16[SP3];                          // bf16 af (static idx)
  float t[SP3];                               // per-lane sim partials
  float4 acc;                                 // current point's af accumulator

  float4 bA00, bA01, bA10, bA11;              // ping buffer
  float4 bB00, bB01, bB10, bB11;              // pong buffer

  auto issue = [&](int k, float4& b00, float4& b01, float4& b10, float4& b11) {
    const int pl = k % 3;
    const int p  = (k / 3) * NH + h;
    const float* P = pl == 0 ? P0 : (pl == 1 ? P1 : P2);
    int i00 = s_si[p * 3 + pl][0];
    int dxo = s_si[p * 3 + pl][1];
    int dyo = s_si[p * 3 + pl][2];
    b00 = *(const float4*)(P + i00);
    b01 = *(const float4*)(P + i00 + dxo);
    b10 = *(const float4*)(P + i00 + dyo);
    b11 = *(const float4*)(P + i00 + dyo + dxo);
  };
  auto consume = [&](int k, float4& b00, float4& b01, float4& b10, float4& b11) {
    const int pl = k % 3, jj = k / 3;
    const int p  = jj * NH + h;
    float w0 = s_sw[p * 3 + pl][0], w1 = s_sw[p * 3 + pl][1];
    float w2 = s_sw[p * 3 + pl][2], w3 = s_sw[p * 3 + pl][3];
    if (pl == 0) { acc.x = 0.f; acc.y = 0.f; acc.z = 0.f; acc.w = 0.f; }
    acc.x = fmaf(w0, b00.x, fmaf(w1, b01.x, fmaf(w2, b10.x, fmaf(w3, b11.x, acc.x))));
    acc.y = fmaf(w0, b00.y, fmaf(w1, b01.y, fmaf(w2, b10.y, fmaf(w3, b11.y, acc.y))));
    acc.z = fmaf(w0, b00.z, fmaf(w1, b01.z, fmaf(w2, b10.z, fmaf(w3, b11.z, acc.z))));
    acc.w = fmaf(w0, b00.w, fmaf(w1, b01.w, fmaf(w2, b10.w, fmaf(w3, b11.w, acc.w))));
    if (pl == 2) {
      ushort4 hh;
      hh.x = f2bf(acc.x); hh.y = f2bf(acc.y); hh.z = f2bf(acc.z); hh.w = f2bf(acc.w);
      af16[jj] = hh;
      t[jj] = fmaf(qk4.x, acc.x, fmaf(qk4.y, acc.y, fmaf(qk4.z, acc.z, qk4.w * acc.w)));
    }
  };

  issue(0, bA00, bA01, bA10, bA11);
  #pragma unroll
  for (int k = 0; k < 24; k += 2) {
    if (k + 1 < 24) issue(k + 1, bB00, bB01, bB10, bB11);
    consume(k, bA00, bA01, bA10, bA11);
    if (k + 2 < 24) issue(k + 2, bA00, bA01, bA10, bA11);
    if (k + 1 < 24) consume(k + 1, bB00, bB01, bB10, bB11);
  }

  #pragma unroll
  for (int o = 32; o >= 1; o >>= 1) {
    #pragma unroll
    for (int jj = 0; jj < SP3; jj++) t[jj] += __shfl_xor(t[jj], o, 64);
  }

  float m = -1e30f;
  #pragma unroll
  for (int jj = 0; jj < SP3; jj++) m = fmaxf(m, t[jj]);
  float sum = 0.f;
  #pragma unroll
  for (int jj = 0; jj < SP3; jj++) { t[jj] = __expf(t[jj] - m); sum += t[jj]; }
  float inv = 1.0f / sum;
  float4 r; r.x = 0.f; r.y = 0.f; r.z = 0.f; r.w = 0.f;
  #pragma unroll
  for (int jj = 0; jj < SP3; jj++) {
    float av = t[jj] * inv;
    ushort4 hv = af16[jj];
    r.x = fmaf(av, bf2f(hv.x), r.x);
    r.y = fmaf(av, bf2f(hv.y), r.y);
    r.z = fmaf(av, bf2f(hv.z), r.z);
    r.w = fmaf(av, bf2f(hv.w), r.w);
  }
  *(float4*)(s_wf + h * FD + c4) = r;         // was the wf global write
  __syncthreads();

  // ---- stage 5A: o[h*64+e] = b_v[e] + sum_c wf[h][c] * w_v[c][e]
  {
    const int hh = tid >> 6, e = tid & 63;
    float a5 = b_v[e];
    const float* wrow = s_wf + hh * FD;
    for (int c = 0; c < FD; c++)
      a5 = fmaf(wrow[c], w_v[(size_t)c * EDIM + e], a5);  // epik phase-A order
    s_o[tid] = a5;                            // tid == hh*EDIM+e
  }
  __syncthreads();

  // ---- stage 5B: out[d] = b_out[d] + sum_c o[c]*w_out[c][d] + feat[d]
  {
    float r5 = b_out[tid];
    for (int c = 0; c < FD; c++)
      r5 = fmaf(s_o[c], w_out[(size_t)c * FD + tid], r5);  // epik phase-B order
    out[qg * FD + tid] = r5 + s_feat[tid];
  }
}

// ---------------------------------------------------------------------------
extern "C" void kernel_launch(void* const* d_in, const int* in_sizes, int n_in,
                              void* d_out, int out_size, void* d_ws, size_t ws_size,
                              hipStream_t stream) {
  const float* qp    = (const float*)d_in[0];
  const float* cxz   = (const float*)d_in[1];
  const float* cxy   = (const float*)d_in[2];
  const float* cyz   = (const float*)d_in[3];
  const float* w_off = (const float*)d_in[4];
  const float* b_off = (const float*)d_in[5];
  const float* w_q   = (const float*)d_in[6];
  const float* b_q   = (const float*)d_in[7];
  const float* w_k   = (const float*)d_in[8];
  const float* b_k   = (const float*)d_in[9];   (void)b_k; // cancels in softmax
  const float* w_v   = (const float*)d_in[10];
  const float* b_v   = (const float*)d_in[11];
  const float* w_out = (const float*)d_in[12];
  const float* b_out = (const float*)d_in[13];
  float* out = (float*)d_out;
  (void)in_sizes; (void)n_in; (void)out_size; (void)ws_size;

  float* ws      = (float*)d_ws;
  float* planesT = ws + WS_PLANES;
  unsigned* perm = (unsigned*)(ws + WS_PERM);

  hipLaunchKernelGGL(sortk, dim3(BS / PAIR_B), dim3(1024), 0, stream, qp, perm);

  for (int pair = 0; pair < BS / PAIR_B; ++pair) {
    int b0 = pair * PAIR_B;
    hipLaunchKernelGGL(tpk2, dim3(3 * PAIR_B * 512), dim3(256), 0, stream,
                       cxz, cxy, cyz, planesT, b0);
    hipLaunchKernelGGL(fusedk, dim3(PAIR_Q), dim3(256), 0, stream,
                       qp, planesT, w_off, b_off, w_q, b_q, w_k,
                       w_v, b_v, w_out, b_out,
                       perm + (size_t)pair * PAIR_Q, out, b0);
  }
}

// Round 6
// 484.102 us; speedup vs baseline: 1.0733x; 1.0027x over previous
//
#include <hip/hip_runtime.h>
#include <math.h>

// Problem constants
#define FD   256
#define NH   4
#define SP3  8
#define NP   32          // SP3*NH aux points per query
#define EDIM 64          // FD/NH
#define H    128
#define NS   1024
#define BS   4

#define TEX         (H*H)              // 16384 texels per (plane,b)
#define BATCH_ELEMS (TEX*FD)           // 4,194,304 floats
#define PAIR_B      2                  // batches processed per pass
#define PAIR_Q      (PAIR_B*NS)        // 2048 queries per pass
#define PPLANE      (PAIR_B*BATCH_ELEMS) // per-plane elems in pair buffer

// ---- workspace layout (float offsets). Total ~114.05 MB (layout kept from
// the proven rounds; feat/qk/aux/wf slots now unused after fusion).
#define WS_PLANES 0
#define WS_FEAT   (3*PPLANE)                       // [2048][256] (unused)
#define WS_QK     (WS_FEAT + PAIR_Q*FD)            // [2048][256] (unused)
#define WS_AUX    (WS_QK   + PAIR_Q*FD)            // [2048][96]  (unused)
#define WS_WF     (WS_AUX  + PAIR_Q*NP*3)          // [2048][4][256] (unused)
#define WS_PERM   (WS_WF   + PAIR_Q*NH*FD)         // [2 pairs][2048] uint

// bf16 helpers (round-to-nearest-even). Used ONLY on the wf path (af after
// the fp32 sim dot) — sim-path quantization is amplified ~176x and is fatal.
__device__ __forceinline__ unsigned short f2bf(float f) {
  unsigned b = __float_as_uint(f);
  return (unsigned short)((b + 0x7FFFu + ((b >> 16) & 1u)) >> 16);
}
__device__ __forceinline__ float bf2f(unsigned short u) {
  return __uint_as_float(((unsigned)u) << 16);
}

// ---------------------------------------------------------------------------
// K1: transpose planes [B,C,H,W] -> [b-pair][H*W,C] (channel-last).
// 32-texel x 256-channel tiles; LDS 33 KB -> 4 blocks/CU.
// ---------------------------------------------------------------------------
__global__ __launch_bounds__(256) void tpk2(
    const float* __restrict__ xz, const float* __restrict__ xy,
    const float* __restrict__ yz, float* __restrict__ dstAll, int b0)
{
  int bid = blockIdx.x;
  int tT = bid & 511; bid >>= 9;     // 512 texel-tiles of 32
  int bl = bid & 1;   bid >>= 1;     // local batch in pair
  int pl = bid;                      // plane
  const float* src = pl == 0 ? xz : (pl == 1 ? xy : yz);
  float* dst = dstAll + (size_t)pl * PPLANE + (size_t)bl * BATCH_ELEMS;
  int b = b0 + bl;

  __shared__ float T[32 * 260];      // T[texel][channel], stride 260
  int lane = threadIdx.x & 63, w = threadIdx.x >> 6;
  int tex4 = (lane & 7) * 4;         // 0,4,..,28
  int csub = lane >> 3;              // 0..7

  const float* sbase = src + (size_t)b * FD * TEX + tT * 32;
  #pragma unroll
  for (int i = 0; i < 8; i++) {
    int c = i * 32 + w * 8 + csub;   // covers 0..255
    float4 v = *(const float4*)(sbase + (size_t)c * TEX + tex4);
    T[(tex4 + 0) * 260 + c] = v.x;
    T[(tex4 + 1) * 260 + c] = v.y;
    T[(tex4 + 2) * 260 + c] = v.z;
    T[(tex4 + 3) * 260 + c] = v.w;
  }
  __syncthreads();
  #pragma unroll
  for (int i = 0; i < 8; i++) {
    int t = w * 8 + i;
    float4 v = *(const float4*)(&T[t * 260 + lane * 4]);
    *(float4*)(dst + (size_t)(tT * 32 + t) * FD + lane * 4) = v;  // 1KB/wave
  }
}

// ---------------------------------------------------------------------------
// K1b: counting-sort the pair's 2048 queries into 256 buckets =
// (batch<<7)|top-7-Morton-bits. One block per pair, O(n).
// ---------------------------------------------------------------------------
__device__ __forceinline__ unsigned mort7(unsigned v) {   // 7 bits -> every 3rd
  unsigned r = 0;
  #pragma unroll
  for (int i = 0; i < 7; i++) r |= ((v >> i) & 1u) << (3 * i);
  return r;
}

__global__ __launch_bounds__(1024) void sortk(
    const float* __restrict__ qpos, unsigned* __restrict__ perm)
{
  const int pair = blockIdx.x;
  const int b0 = pair * PAIR_B;
  const int t = threadIdx.x;
  __shared__ unsigned cnt[256];
  __shared__ unsigned base[256];
  if (t < 256) cnt[t] = 0;
  __syncthreads();
  unsigned myb[2];
  #pragma unroll
  for (int r = 0; r < 2; r++) {
    int i = t + r * 1024;
    size_t qg = (size_t)b0 * NS + i;
    float x = fminf(fmaxf(qpos[qg * 3 + 0], 0.f), 1.f);
    float y = fminf(fmaxf(qpos[qg * 3 + 1], 0.f), 1.f);
    float z = fminf(fmaxf(qpos[qg * 3 + 2], 0.f), 1.f);
    unsigned m = (mort7((unsigned)(x * 127.f)) << 2)
               | (mort7((unsigned)(y * 127.f)) << 1)
               |  mort7((unsigned)(z * 127.f));          // 21 bits
    unsigned bkt = ((unsigned)(i >> 10) << 7) | (m >> 14);
    myb[r] = bkt;
    atomicAdd(&cnt[bkt], 1u);
  }
  __syncthreads();
  if (t == 0) {
    unsigned s = 0;
    for (int k = 0; k < 256; k++) { base[k] = s; s += cnt[k]; }
  }
  __syncthreads();
  #pragma unroll
  for (int r = 0; r < 2; r++) {
    int i = t + r * 1024;
    unsigned pos = atomicAdd(&base[myb[r]], 1u);
    perm[(size_t)pair * PAIR_Q + pos] = (unsigned)i;
  }
}

// ---------------------------------------------------------------------------
// Bilinear helpers (channel-last plane)
// ---------------------------------------------------------------------------
__device__ __forceinline__ float sample_plane(const float* __restrict__ p,
                                              float u, float v) {
  float x = fminf(fmaxf(u, 0.f), 1.f) * (float)(H - 1);
  float y = fminf(fmaxf(v, 0.f), 1.f) * (float)(H - 1);
  float xf = floorf(x), yf = floorf(y);
  int x0 = (int)xf, y0 = (int)yf;
  float wx = x - xf, wy = y - yf;
  int dx = (x0 < H - 1) ? FD : 0;
  int dy = (y0 < H - 1) ? H * FD : 0;
  int i00 = (y0 * H + x0) * FD;
  float f00 = p[i00], f01 = p[i00 + dx], f10 = p[i00 + dy], f11 = p[i00 + dy + dx];
  float a = f00 + wx * (f01 - f00);
  float b = f10 + wx * (f11 - f10);
  return a + wy * (b - a);
}

__device__ __forceinline__ void setup_samp(int* si, float* sw, float u, float v) {
  float x = fminf(fmaxf(u, 0.f), 1.f) * (float)(H - 1);
  float y = fminf(fmaxf(v, 0.f), 1.f) * (float)(H - 1);
  float xf = floorf(x), yf = floorf(y);
  int x0 = (int)xf, y0 = (int)yf;
  float wx = x - xf, wy = y - yf;
  si[0] = (y0 * H + x0) * FD;
  si[1] = (x0 < H - 1) ? FD : 0;
  si[2] = (y0 < H - 1) ? H * FD : 0;
  sw[0] = (1.f - wy) * (1.f - wx);
  sw[1] = (1.f - wy) * wx;
  sw[2] = wy * (1.f - wx);
  sw[3] = wy * wx;
}

// ---------------------------------------------------------------------------
// K3 (FUSED, hot): one query per block; featk + attnk + epik in one kernel.
// ROUND-6 CHANGE: r5's fusion compiled the gather to VGPR=32 (vs r4's 40) —
// the ping-pong buffers lost liveness and the fetch rate dropped 3.45 ->
// 2.27 TB/s (fusedk 129 us ~= 267MB / 2.27TB/s + serial stages). Fix: force
// pipeline depth with FOUR named quad-buffer sets (prologue issues quads
// 0..3; steady state consume(k), issue(k+4) -> 16 loads in flight per wave),
// and launch_bounds(256,4) (VGPR cap 128; ~100 needed — at (256,6)'s cap 85
// this would spill). 16 waves/CU x 16 in flight >> the ~26 lines/CU needed
// to saturate the observed 3.45 TB/s fetch wall (r2: 16 waves sufficed).
// FP accumulation orders unchanged everywhere (absmax must stay 0.1279297).
// ---------------------------------------------------------------------------
__global__ __launch_bounds__(256, 4) void fusedk(
    const float* __restrict__ qpos, const float* __restrict__ planesT,
    const float* __restrict__ w_off, const float* __restrict__ b_off,
    const float* __restrict__ w_q, const float* __restrict__ b_q,
    const float* __restrict__ w_k,
    const float* __restrict__ w_v, const float* __restrict__ b_v,
    const float* __restrict__ w_out, const float* __restrict__ b_out,
    const unsigned* __restrict__ perm, float* __restrict__ out, int b0)
{
  const int tid = threadIdx.x, lane = tid & 63, w = tid >> 6;
  const int bid = blockIdx.x;                 // 0..2047
  const int j = ((bid & 7) << 8) | (bid >> 3);  // XCD-chunked swizzle
  const int c4 = lane * 4;

  __shared__ float s_feat[FD];        // 1 KB   (query feature; lives to stage5)
  __shared__ float s_aux[96];         // aux coords
  __shared__ float s_q[EDIM];         // scaled q
  __shared__ float s_qk[FD];          // qk row
  __shared__ int   s_si[96][3];
  __shared__ float s_sw[96][4];
  __shared__ float s_wf[NH * FD];     // 4 KB   (per-head attn output)
  __shared__ float s_o[FD];           // o = concat-head @ w_v

  const int qw = (int)perm[j];                // this block's query (uniform)
  const int blw = qw >> 10;
  const size_t qg = (size_t)b0 * NS + qw;     // global query row
  const float px = qpos[qg * 3 + 0];
  const float py = qpos[qg * 3 + 1];
  const float pz = qpos[qg * 3 + 2];

  const float* Pxz = planesT + 0 * (size_t)PPLANE + (size_t)blw * BATCH_ELEMS;
  const float* Pxy = planesT + 1 * (size_t)PPLANE + (size_t)blw * BATCH_ELEMS;
  const float* Pyz = planesT + 2 * (size_t)PPLANE + (size_t)blw * BATCH_ELEMS;

  // ---- stage 1: feature at query pos (thread = channel; same op order as featk)
  {
    float f = sample_plane(Pxz + tid, px, pz) + sample_plane(Pxy + tid, px, py)
            + sample_plane(Pyz + tid, py, pz);
    s_feat[tid] = f;
  }
  __syncthreads();

  // ---- stage 2: unified 256-dot. Uniform loop body (no divergence inside),
  // divergent only in base pointer/stride/bias.
  if (tid < 160) {
    const bool isOff = tid < 96;
    const int  col   = isOff ? tid : (tid - 96);
    const float* Wp  = isOff ? (w_off + col) : (w_q + col);
    const int  strd  = isOff ? 96 : EDIM;
    float acc = isOff ? b_off[col] : b_q[col];
    for (int c = 0; c < FD; c++) {
      acc = fmaf(s_feat[c], *Wp, acc);
      Wp += strd;
    }
    if (isOff) {
      int d = col % 3;
      float qp = (d == 0) ? px : ((d == 1) ? py : pz);
      s_aux[col] = acc + qp;
    } else {
      s_q[col] = acc * 8.0f;          // scaled by sqrt(E)=8 (b_k cancels)
    }
  }
  __syncthreads();

  // ---- stage 3: qk[c] (all 256 threads) + setup_samp (tid<96)
  {
    float acc = 0.f;
    const float* wk = w_k + (size_t)tid * EDIM;
    for (int e = 0; e < EDIM; e++)
      acc = fmaf(s_q[e], wk[e], acc);  // e ascending == featk's float4 order
    s_qk[tid] = acc;
  }
  if (tid < 96) {
    int p = tid / 3, pl = tid - p * 3;
    float ax = s_aux[p * 3 + 0];
    float ay = s_aux[p * 3 + 1];
    float az = s_aux[p * 3 + 2];
    float u = (pl == 2) ? ay : ax;   // pl0:(ax,az) pl1:(ax,ay) pl2:(ay,az)
    float v = (pl == 1) ? ay : az;
    setup_samp(s_si[tid], s_sw[tid], u, v);
  }
  __syncthreads();

  // ---- stage 4: 4-deep pipelined gather + wave-uniform softmax.
  const int h = w;                            // wave = head
  float4 qk4 = *(const float4*)(s_qk + c4);
  const float* P0 = Pxz + c4;
  const float* P1 = Pxy + c4;
  const float* P2 = Pyz + c4;

  ushort4 af16[SP3];                          // bf16 af (static idx)
  float t[SP3];                               // per-lane sim partials
  float4 acc;                                 // current point's af accumulator

  // four named buffer sets -> 16 loads in flight
  float4 s0_00, s0_01, s0_10, s0_11;
  float4 s1_00, s1_01, s1_10, s1_11;
  float4 s2_00, s2_01, s2_10, s2_11;
  float4 s3_00, s3_01, s3_10, s3_11;

  auto issue = [&](int k, float4& b00, float4& b01, float4& b10, float4& b11) {
    const int pl = k % 3;
    const int p  = (k / 3) * NH + h;
    const float* P = pl == 0 ? P0 : (pl == 1 ? P1 : P2);
    int i00 = s_si[p * 3 + pl][0];
    int dxo = s_si[p * 3 + pl][1];
    int dyo = s_si[p * 3 + pl][2];
    b00 = *(const float4*)(P + i00);
    b01 = *(const float4*)(P + i00 + dxo);
    b10 = *(const float4*)(P + i00 + dyo);
    b11 = *(const float4*)(P + i00 + dyo + dxo);
  };
  auto consume = [&](int k, float4& b00, float4& b01, float4& b10, float4& b11) {
    const int pl = k % 3, jj = k / 3;
    const int p  = jj * NH + h;
    float w0 = s_sw[p * 3 + pl][0], w1 = s_sw[p * 3 + pl][1];
    float w2 = s_sw[p * 3 + pl][2], w3 = s_sw[p * 3 + pl][3];
    if (pl == 0) { acc.x = 0.f; acc.y = 0.f; acc.z = 0.f; acc.w = 0.f; }
    acc.x = fmaf(w0, b00.x, fmaf(w1, b01.x, fmaf(w2, b10.x, fmaf(w3, b11.x, acc.x))));
    acc.y = fmaf(w0, b00.y, fmaf(w1, b01.y, fmaf(w2, b10.y, fmaf(w3, b11.y, acc.y))));
    acc.z = fmaf(w0, b00.z, fmaf(w1, b01.z, fmaf(w2, b10.z, fmaf(w3, b11.z, acc.z))));
    acc.w = fmaf(w0, b00.w, fmaf(w1, b01.w, fmaf(w2, b10.w, fmaf(w3, b11.w, acc.w))));
    if (pl == 2) {
      ushort4 hh;
      hh.x = f2bf(acc.x); hh.y = f2bf(acc.y); hh.z = f2bf(acc.z); hh.w = f2bf(acc.w);
      af16[jj] = hh;
      t[jj] = fmaf(qk4.x, acc.x, fmaf(qk4.y, acc.y, fmaf(qk4.z, acc.z, qk4.w * acc.w)));
    }
  };

  // prologue: fill all four slots (quads 0..3 in flight)
  issue(0, s0_00, s0_01, s0_10, s0_11);
  issue(1, s1_00, s1_01, s1_10, s1_11);
  issue(2, s2_00, s2_01, s2_10, s2_11);
  issue(3, s3_00, s3_01, s3_10, s3_11);

  // steady state: consume quad k from slot k&3, refill with quad k+4
#define PIPE(k, S) do {                                         \
    consume(k, S##_00, S##_01, S##_10, S##_11);                 \
    if ((k) + 4 < 24) issue((k) + 4, S##_00, S##_01, S##_10, S##_11); \
  } while (0)

  PIPE(0,  s0); PIPE(1,  s1); PIPE(2,  s2); PIPE(3,  s3);
  PIPE(4,  s0); PIPE(5,  s1); PIPE(6,  s2); PIPE(7,  s3);
  PIPE(8,  s0); PIPE(9,  s1); PIPE(10, s2); PIPE(11, s3);
  PIPE(12, s0); PIPE(13, s1); PIPE(14, s2); PIPE(15, s3);
  PIPE(16, s0); PIPE(17, s1); PIPE(18, s2); PIPE(19, s3);
  PIPE(20, s0); PIPE(21, s1); PIPE(22, s2); PIPE(23, s3);
#undef PIPE

  #pragma unroll
  for (int o = 32; o >= 1; o >>= 1) {
    #pragma unroll
    for (int jj = 0; jj < SP3; jj++) t[jj] += __shfl_xor(t[jj], o, 64);
  }

  float m = -1e30f;
  #pragma unroll
  for (int jj = 0; jj < SP3; jj++) m = fmaxf(m, t[jj]);
  float sum = 0.f;
  #pragma unroll
  for (int jj = 0; jj < SP3; jj++) { t[jj] = __expf(t[jj] - m); sum += t[jj]; }
  float inv = 1.0f / sum;
  float4 r; r.x = 0.f; r.y = 0.f; r.z = 0.f; r.w = 0.f;
  #pragma unroll
  for (int jj = 0; jj < SP3; jj++) {
    float av = t[jj] * inv;
    ushort4 hv = af16[jj];
    r.x = fmaf(av, bf2f(hv.x), r.x);
    r.y = fmaf(av, bf2f(hv.y), r.y);
    r.z = fmaf(av, bf2f(hv.z), r.z);
    r.w = fmaf(av, bf2f(hv.w), r.w);
  }
  *(float4*)(s_wf + h * FD + c4) = r;         // was the wf global write
  __syncthreads();

  // ---- stage 5A: o[h*64+e] = b_v[e] + sum_c wf[h][c] * w_v[c][e]
  {
    const int hh = tid >> 6, e = tid & 63;
    float a5 = b_v[e];
    const float* wrow = s_wf + hh * FD;
    for (int c = 0; c < FD; c++)
      a5 = fmaf(wrow[c], w_v[(size_t)c * EDIM + e], a5);  // epik phase-A order
    s_o[tid] = a5;                            // tid == hh*EDIM+e
  }
  __syncthreads();

  // ---- stage 5B: out[d] = b_out[d] + sum_c o[c]*w_out[c][d] + feat[d]
  {
    float r5 = b_out[tid];
    for (int c = 0; c < FD; c++)
      r5 = fmaf(s_o[c], w_out[(size_t)c * FD + tid], r5);  // epik phase-B order
    out[qg * FD + tid] = r5 + s_feat[tid];
  }
}

// ---------------------------------------------------------------------------
extern "C" void kernel_launch(void* const* d_in, const int* in_sizes, int n_in,
                              void* d_out, int out_size, void* d_ws, size_t ws_size,
                              hipStream_t stream) {
  const float* qp    = (const float*)d_in[0];
  const float* cxz   = (const float*)d_in[1];
  const float* cxy   = (const float*)d_in[2];
  const float* cyz   = (const float*)d_in[3];
  const float* w_off = (const float*)d_in[4];
  const float* b_off = (const float*)d_in[5];
  const float* w_q   = (const float*)d_in[6];
  const float* b_q   = (const float*)d_in[7];
  const float* w_k   = (const float*)d_in[8];
  const float* b_k   = (const float*)d_in[9];   (void)b_k; // cancels in softmax
  const float* w_v   = (const float*)d_in[10];
  const float* b_v   = (const float*)d_in[11];
  const float* w_out = (const float*)d_in[12];
  const float* b_out = (const float*)d_in[13];
  float* out = (float*)d_out;
  (void)in_sizes; (void)n_in; (void)out_size; (void)ws_size;

  float* ws      = (float*)d_ws;
  float* planesT = ws + WS_PLANES;
  unsigned* perm = (unsigned*)(ws + WS_PERM);

  hipLaunchKernelGGL(sortk, dim3(BS / PAIR_B), dim3(1024), 0, stream, qp, perm);

  for (int pair = 0; pair < BS / PAIR_B; ++pair) {
    int b0 = pair * PAIR_B;
    hipLaunchKernelGGL(tpk2, dim3(3 * PAIR_B * 512), dim3(256), 0, stream,
                       cxz, cxy, cyz, planesT, b0);
    hipLaunchKernelGGL(fusedk, dim3(PAIR_Q), dim3(256), 0, stream,
                       qp, planesT, w_off, b_off, w_q, b_q, w_k,
                       w_v, b_v, w_out, b_out,
                       perm + (size_t)pair * PAIR_Q, out, b0);
  }
}